// Round 7
// baseline (165.931 us; speedup 1.0000x reference)
//
#include <hip/hip_runtime.h>
#include <hip/hip_bf16.h>
#include <math.h>

// Problem constants
#define PS    32768
#define DIN   1024
#define DMID  512
#define DATT  128
#define KMASK 16384
#define LKEEP 16384

typedef unsigned short u16;
typedef __attribute__((ext_vector_type(8))) short short8;
typedef __attribute__((ext_vector_type(4))) float f32x4;

__device__ __forceinline__ u16 f2bf(float f){
  unsigned x = __float_as_uint(f);
  unsigned r = (x + 0x7fffu + ((x >> 16) & 1u)) >> 16;  // RNE
  return (u16)r;
}
__device__ __forceinline__ u16 f2bf_hw(float f){
  __hip_bfloat16 h = __float2bfloat16(f);    // RNE; pairs fuse to v_cvt_pk_bf16_f32
  return *reinterpret_cast<u16*>(&h);
}
__device__ __forceinline__ float bf2f(u16 u){
  return __uint_as_float(((unsigned)u) << 16);
}
// monotonic key: larger float -> larger unsigned
__device__ __forceinline__ unsigned fkey(float f){
  unsigned b = __float_as_uint(f);
  return (b & 0x80000000u) ? ~b : (b | 0x80000000u);
}

#define GLDS16(g,l) __builtin_amdgcn_global_load_lds( \
    (const __attribute__((address_space(1))) void*)(g), \
    (__attribute__((address_space(3))) void*)(l), 16, 0, 0)

// ---------------------------------------------------------------------------
// ctrl layout (ints): [2]=C (cutoff key), [3]=eqidx_thr.
// kept(u,idx) = (u < C) || (u == C && idx > eqidx_thr).
// ---------------------------------------------------------------------------

// Prep: both weight transposes (f32->bf16) + zero hist/ctrl. 576 blocks.
__global__ __launch_bounds__(256) void k_prep(const float* __restrict__ Wemb,
                                              u16* __restrict__ wet,
                                              const float* __restrict__ Wa1,
                                              u16* __restrict__ wa1t,
                                              int* __restrict__ zbuf){
  __shared__ float tile[32][33];
  const int b = blockIdx.x, t = threadIdx.x;
  const int flat = b * 256 + t;
  if (flat < 16384 + 64) zbuf[flat] = 0;
  const int tx = t & 31, ty = t >> 5;
  if (b < 512){
    const int c0 = (b & 15) * 32, r0 = (b >> 4) * 32;   // Wemb [1024][512]
    for (int i = 0; i < 32; i += 8)
      tile[ty + i][tx] = Wemb[(size_t)(r0 + ty + i) * DMID + c0 + tx];
    __syncthreads();
    for (int i = 0; i < 32; i += 8)
      wet[(size_t)(c0 + ty + i) * DIN + r0 + tx] = f2bf(tile[tx][ty + i]);
  } else {
    const int b2 = b - 512;                              // Wa1 [512][128]
    const int c0 = (b2 & 3) * 32, r0 = (b2 >> 2) * 32;
    for (int i = 0; i < 32; i += 8)
      tile[ty + i][tx] = Wa1[(size_t)(r0 + ty + i) * DATT + c0 + tx];
    __syncthreads();
    for (int i = 0; i < 32; i += 8)
      wa1t[(size_t)(c0 + ty + i) * DMID + r0 + tx] = f2bf(tile[tx][ty + i]);
  }
}

// Stage 1: 14-bit global histogram. 32 blocks x 1024.
__global__ __launch_bounds__(1024) void k_sel_hist(const float* __restrict__ attn,
                                                   int* __restrict__ hist){
  const int i = blockIdx.x * 1024 + threadIdx.x;
  const unsigned u = fkey(attn[i]);
  atomicAdd(&hist[u >> 18], 1);
}

// Stage 2+3 merged: suffix-scan 16384 bins -> (B, kprime); then collect bin-B
// candidates into LDS and rank-select the (kp-1)-th under (key desc, idx asc)
// -> exact cutoff C and tie-threshold index thr. One block x 1024.
__global__ __launch_bounds__(1024) void k_sel_scanrefine(const float* __restrict__ attn,
                                                         const int* __restrict__ hist,
                                                         int* __restrict__ ctrl){
  __shared__ int suf[1024];
  __shared__ unsigned ck[4096];
  __shared__ int ci[4096];
  __shared__ int sh_B, sh_kp, cnt;
  const int t = threadIdx.x;
  int local[16]; int s = 0;
  const int base = t * 16;
  for (int j = 0; j < 16; j++){ local[j] = hist[base + j]; s += local[j]; }
  suf[t] = s; __syncthreads();
  for (int off = 1; off < 1024; off <<= 1){
    int v = (t + off < 1024) ? suf[t + off] : 0;
    __syncthreads();
    suf[t] += v;
    __syncthreads();
  }
  const int above = (t < 1023) ? suf[t + 1] : 0;
  if (above < KMASK && KMASK <= suf[t]){
    int cum = above;
    for (int b = 15; b >= 0; b--){
      int c = local[b];
      if (cum + c >= KMASK){ sh_B = base + b; sh_kp = KMASK - cum; break; }
      cum += c;
    }
  }
  if (t == 0) cnt = 0;
  __syncthreads();
  const unsigned B = (unsigned)sh_B;
  const int kp = sh_kp;
  for (int i = t; i < PS; i += 1024){
    unsigned u = fkey(attn[i]);
    if ((u >> 18) == B){
      int p = atomicAdd(&cnt, 1);
      if (p < 4096){ ck[p] = u; ci[p] = i; }
    }
  }
  __syncthreads();
  int n = cnt; if (n > 4096) n = 4096;
  for (int p = t; p < n; p += 1024){
    const unsigned mk = ck[p]; const int mi = ci[p];
    int rank = 0;
    for (int j = 0; j < n; j++){
      const unsigned kj = ck[j];
      rank += (kj > mk) || (kj == mk && ci[j] < mi);
    }
    if (rank == kp - 1){ ctrl[2] = (int)mk; ctrl[3] = mi; }
  }
}

// Stage 4 merged cnt+write: each block recomputes prior chunks' keep counts
// (L2-hot, <=31 extra elements/thread) -> base; then stable compacted write.
__global__ __launch_bounds__(1024) void k_sel_cntwrite(const float* __restrict__ attn,
                                                       const int* __restrict__ ctrl,
                                                       int* __restrict__ keep_ids){
  __shared__ int red[1024];
  __shared__ int wbase[16];
  __shared__ int sh_base;
  const int t = threadIdx.x, b = blockIdx.x;
  const unsigned C = (unsigned)ctrl[2];
  const int thr = ctrl[3];
  const int i = b * 1024 + t;
  const unsigned u = fkey(attn[i]);
  const bool kept = (u < C) || (u == C && i > thr);
  const unsigned long long bal = __ballot(kept);
  const int lane = t & 63, w = t >> 6;
  if (lane == 0) wbase[w] = __popcll(bal);
  // count kept in chunks 0..b-1
  int cnt = 0;
  for (int j = 0; j < b; j++){
    const int i2 = j * 1024 + t;
    const unsigned u2 = fkey(attn[i2]);
    cnt += (u2 < C) || (u2 == C && i2 > thr);
  }
  red[t] = cnt; __syncthreads();
  for (int st = 512; st > 0; st >>= 1){ if (t < st) red[t] += red[t + st]; __syncthreads(); }
  if (t == 0){
    sh_base = red[0];
    int run = 0;
    for (int j = 0; j < 16; j++){ int c = wbase[j]; wbase[j] = run; run += c; }
  }
  __syncthreads();
  if (kept){
    const int lr = __popcll(bal & ((1ull << lane) - 1ull));
    keep_ids[sh_base + wbase[w] + lr] = i;
  }
}

// ---------------------------------------------------------------------------
// GEMM1 fused with gather: h = relu(x[keep] @ W_emb + b_emb) -> bf16
// 128x128 tile, BK=32, 4 waves, mfma 16x16x32 bf16.
// A staged as f32 via global_load_lds with SOURCE-side XOR swizzle:
//   physical LDS byte p = logical ^ ((row&7)<<4)  (involution, bits 4-6)
//   stage: lane l, instr q -> row = wid*32+q*8+(l>>3), col chunk (l&7)^(l>>3)
//   read : fragment floats at p0 = (r*128+g*32)^((r&7)<<4) and p0^16 (2-way ok)
// B staged bf16 via global_load_lds (unchanged, linear).
// XCD swizzle keeps the 4 col-blocks of a row-panel on one XCD (A L2-hot).
// ---------------------------------------------------------------------------
__global__ __launch_bounds__(256) void k_gemm1g(const float* __restrict__ xg,
                                                const int* __restrict__ keep,
                                                const u16* __restrict__ wet,
                                                const float* __restrict__ bemb,
                                                u16* __restrict__ hbf){
  __shared__ __align__(16) float Asf[128 * 32];   // 16 KB, swizzled
  __shared__ __align__(16) u16  Bs[128 * 32];     // 8 KB
  const int t = threadIdx.x;
  const int wid = t >> 6, lane = t & 63;
  const int g = lane >> 4, li = lane & 15;
  // swizzle: m%8 = XCD; y = (m&7) + 8*(m>>5); x = (m>>3)&3
  const int m_ = blockIdx.x;
  const int by = (m_ & 7) + 8 * (m_ >> 5);
  const int bx = (m_ >> 3) & 3;
  const int brow = by * 128, bcol = bx * 128;
  const int wrow0 = (wid >> 1) * 64, wcol0 = (wid & 1) * 64;

  f32x4 acc[4][4];
  for (int mm = 0; mm < 4; mm++)
    for (int nn = 0; nn < 4; nn++)
      acc[mm][nn] = (f32x4){0.f, 0.f, 0.f, 0.f};

  // A staging source pointers (per lane, per q-instr)
  const int rsub = lane >> 3;                 // 0..7
  const int c4   = (lane & 7) ^ rsub;         // swizzled 16B chunk index
  const float* gA[4];
#pragma unroll
  for (int q = 0; q < 4; q++){
    const int rid = keep[brow + wid * 32 + q * 8 + rsub];
    gA[q] = xg + (size_t)rid * DIN + c4 * 4;
  }
  // wave-uniform LDS dests (HW adds lane*16B)
  float* lA0 = Asf + wid * 1024 + 0 * 256;
  float* lA1 = Asf + wid * 1024 + 1 * 256;
  float* lA2 = Asf + wid * 1024 + 2 * 256;
  float* lA3 = Asf + wid * 1024 + 3 * 256;

  // B staging (unchanged)
  const int r4 = lane >> 2, cB = lane & 3;
  const u16* gB = wet + ((size_t)(bcol + wid * 32 + r4) * DIN + cB * 8);
  u16* lB = Bs + wid * 1024;

  const char* Asb = (const char*)Asf;
  for (int k0 = 0; k0 < DIN; k0 += 32){
    GLDS16(gA[0] + k0, lA0);
    GLDS16(gA[1] + k0, lA1);
    GLDS16(gA[2] + k0, lA2);
    GLDS16(gA[3] + k0, lA3);
    GLDS16(gB + k0,            lB);
    GLDS16(gB + 16 * DIN + k0, lB + 512);
    __syncthreads();
    short8 a[4], b[4];
#pragma unroll
    for (int mm = 0; mm < 4; mm++){
      const int r = wrow0 + mm * 16 + li;
      const int p0 = (r * 128 + g * 32) ^ ((li & 7) << 4);
      f32x4 lo = *(const f32x4*)(Asb + p0);
      f32x4 hi = *(const f32x4*)(Asb + (p0 ^ 16));
      short8 av;
      av[0] = (short)f2bf_hw(lo[0]); av[1] = (short)f2bf_hw(lo[1]);
      av[2] = (short)f2bf_hw(lo[2]); av[3] = (short)f2bf_hw(lo[3]);
      av[4] = (short)f2bf_hw(hi[0]); av[5] = (short)f2bf_hw(hi[1]);
      av[6] = (short)f2bf_hw(hi[2]); av[7] = (short)f2bf_hw(hi[3]);
      a[mm] = av;
    }
#pragma unroll
    for (int nn = 0; nn < 4; nn++)
      b[nn] = *(const short8*)&Bs[(wcol0 + nn * 16 + li) * 32 + g * 8];
    for (int mm = 0; mm < 4; mm++)
      for (int nn = 0; nn < 4; nn++)
        acc[mm][nn] = __builtin_amdgcn_mfma_f32_16x16x32_bf16(a[mm], b[nn], acc[mm][nn], 0, 0, 0);
    __syncthreads();
  }

  for (int nn = 0; nn < 4; nn++){
    const int col = bcol + wcol0 + nn * 16 + li;
    const float be = bemb[col];
    for (int mm = 0; mm < 4; mm++){
      const int row0 = brow + wrow0 + mm * 16 + g * 4;
      f32x4 v = acc[mm][nn];
      for (int r = 0; r < 4; r++){
        float val = v[r] + be;
        if (val < 0.f) val = 0.f;
        hbf[(size_t)(row0 + r) * DMID + col] = f2bf(val);
      }
    }
  }
}

// ---------------------------------------------------------------------------
// GEMM2 + fused exact-gelu + W_a2 dot.
// ---------------------------------------------------------------------------
__global__ __launch_bounds__(256) void k_gemm2(const u16* __restrict__ hbf,
                                               const u16* __restrict__ wa1t,
                                               const float* __restrict__ ba1,
                                               const float* __restrict__ wa2,
                                               const float* __restrict__ ba2,
                                               float* __restrict__ s_out){
  __shared__ __align__(16) u16 As[64 * 32];
  __shared__ __align__(16) u16 Bs[128 * 32];
  const int t = threadIdx.x;
  const int wid = t >> 6, lane = t & 63;
  const int g = lane >> 4, li = lane & 15;
  const int brow = blockIdx.x * 64;
  const int wrow0 = (wid >> 1) * 32, wcol0 = (wid & 1) * 64;

  f32x4 acc[2][4];
  for (int m = 0; m < 2; m++)
    for (int n = 0; n < 4; n++)
      acc[m][n] = (f32x4){0.f, 0.f, 0.f, 0.f};

  const int r4 = lane >> 2, c4 = lane & 3;
  const u16* gA = hbf  + ((size_t)(brow + wid * 16 + r4) * DMID + c4 * 8);
  const u16* gB = wa1t + ((size_t)(wid * 32 + r4) * DMID + c4 * 8);
  u16* lA = As + wid * 512;
  u16* lB = Bs + wid * 1024;

  for (int k0 = 0; k0 < DMID; k0 += 32){
    GLDS16(gA + k0,             lA);
    GLDS16(gB + k0,             lB);
    GLDS16(gB + 16 * DMID + k0, lB + 512);
    __syncthreads();
    short8 a[2], b[4];
    for (int m = 0; m < 2; m++)
      a[m] = *(const short8*)&As[(wrow0 + m * 16 + li) * 32 + g * 8];
    for (int n = 0; n < 4; n++)
      b[n] = *(const short8*)&Bs[(wcol0 + n * 16 + li) * 32 + g * 8];
    for (int m = 0; m < 2; m++)
      for (int n = 0; n < 4; n++)
        acc[m][n] = __builtin_amdgcn_mfma_f32_16x16x32_bf16(a[m], b[n], acc[m][n], 0, 0, 0);
    __syncthreads();
  }

  float rsum[2][4] = {{0.f,0.f,0.f,0.f},{0.f,0.f,0.f,0.f}};
  for (int n = 0; n < 4; n++){
    const int col = wcol0 + n * 16 + li;
    const float b1 = ba1[col], w2 = wa2[col];
    for (int m = 0; m < 2; m++){
      f32x4 v = acc[m][n];
      for (int r = 0; r < 4; r++){
        float xv = v[r] + b1;
        float ge = 0.5f * xv * (1.0f + erff(xv * 0.70710678118654752f)); // exact gelu
        rsum[m][r] += ge * w2;
      }
    }
  }
  const float bb = ba2[0];
  for (int m = 0; m < 2; m++){
    for (int r = 0; r < 4; r++){
      float v = rsum[m][r];
      v += __shfl_xor(v, 1); v += __shfl_xor(v, 2);
      v += __shfl_xor(v, 4); v += __shfl_xor(v, 8);
      if (li == 0) s_out[brow + wrow0 + m * 16 + g * 4 + r] = v + bb;
    }
  }
}

// ---------------------------------------------------------------------------
// feat partials with softmax fused: every block recomputes m,Z over L2-hot s
// (deterministic — identical result in all blocks). Grid (8 colblk x 64 rowblk).
// ---------------------------------------------------------------------------
__global__ __launch_bounds__(256) void k_feat1(const u16* __restrict__ hbf,
                                               const float* __restrict__ s,
                                               float* __restrict__ partial){
  __shared__ float r1[256];
  const int t = threadIdx.x;
  float m = -INFINITY;
  for (int i = t; i < LKEEP; i += 256) m = fmaxf(m, s[i]);
  r1[t] = m; __syncthreads();
  for (int st = 128; st > 0; st >>= 1){ if (t < st) r1[t] = fmaxf(r1[t], r1[t + st]); __syncthreads(); }
  m = r1[0]; __syncthreads();
  float z = 0.f;
  for (int i = t; i < LKEEP; i += 256) z += expf(s[i] - m);
  r1[t] = z; __syncthreads();
  for (int st = 128; st > 0; st >>= 1){ if (t < st) r1[t] += r1[t + st]; __syncthreads(); }
  const float invZ = 1.0f / r1[0];
  __syncthreads();

  const int colg = t & 7, rowpar = t >> 3;
  const int c0 = blockIdx.x * 64;
  const int j0 = blockIdx.y * 256;
  float acc[8] = {0.f};
  for (int j = j0 + rowpar; j < j0 + 256; j += 32){
    const float wj = expf(s[j] - m) * invZ;
    short8 hv = *(const short8*)&hbf[(size_t)j * DMID + c0 + colg * 8];
    for (int c = 0; c < 8; c++) acc[c] += wj * bf2f((u16)hv[c]);
  }
  __shared__ float red[256 * 8];
  for (int c = 0; c < 8; c++) red[t * 8 + c] = acc[c];
  __syncthreads();
  for (int st = 128; st >= 8; st >>= 1){
    if (t < st){ for (int c = 0; c < 8; c++) red[t * 8 + c] += red[(t + st) * 8 + c]; }
    __syncthreads();
  }
  if (t < 8){
    for (int c = 0; c < 8; c++)
      partial[(size_t)blockIdx.y * DMID + c0 + t * 8 + c] = red[t * 8 + c];
  }
}

// ---------------------------------------------------------------------------
// Final: feat reduce (64 partials) + logits + soft-CE loss. One block x 512.
// ---------------------------------------------------------------------------
__global__ __launch_bounds__(512) void k_final(const float* __restrict__ partial,
                                               const float* __restrict__ teach,
                                               const float* __restrict__ Wp,
                                               const float* __restrict__ bp,
                                               float* __restrict__ out){
  __shared__ float red[512];
  const int t = threadIdx.x;
  float f = 0.f;
  for (int rb = 0; rb < 64; rb++) f += partial[(size_t)rb * DMID + t];
  const float td = teach[t];

  red[t] = f; __syncthreads();
  for (int st = 256; st > 0; st >>= 1){ if (t < st) red[t] = fmaxf(red[t], red[t + st]); __syncthreads(); }
  const float mf = red[0]; __syncthreads();

  red[t] = td; __syncthreads();
  for (int st = 256; st > 0; st >>= 1){ if (t < st) red[t] = fmaxf(red[t], red[t + st]); __syncthreads(); }
  const float mt = red[0]; __syncthreads();

  red[t] = expf(f - mf); __syncthreads();
  for (int st = 256; st > 0; st >>= 1){ if (t < st) red[t] += red[t + st]; __syncthreads(); }
  const float Zf = red[0]; __syncthreads();

  const float pt = expf(td - mt);
  red[t] = pt; __syncthreads();
  for (int st = 256; st > 0; st >>= 1){ if (t < st) red[t] += red[t + st]; __syncthreads(); }
  const float Zt = red[0]; __syncthreads();

  red[t] = pt * f; __syncthreads();
  for (int st = 256; st > 0; st >>= 1){ if (t < st) red[t] += red[t + st]; __syncthreads(); }
  const float S1 = red[0]; __syncthreads();

  red[t] = f * Wp[t * 2 + 0]; __syncthreads();
  for (int st = 256; st > 0; st >>= 1){ if (t < st) red[t] += red[t + st]; __syncthreads(); }
  const float L0 = red[0]; __syncthreads();

  red[t] = f * Wp[t * 2 + 1]; __syncthreads();
  for (int st = 256; st > 0; st >>= 1){ if (t < st) red[t] += red[t + st]; __syncthreads(); }
  const float L1 = red[0];

  if (t == 0){
    out[0] = L0 + bp[0];
    out[1] = L1 + bp[1];
    out[2] = (mf + logf(Zf)) - S1 / Zt;
  }
}

// ---------------------------------------------------------------------------
// ws layout (bytes):
//   [0)        keep_ids  int[16384]
//   [65536)    s         f32[16384]
//   [131072)   (unused)
//   [200704)   wet       bf16[512][1024]
//   [1249280)  wa1t      bf16[128][512]
//   [1380352)  scratch: hist int[16384] + ctrl int[64] (selection phase),
//              then partial f32[64][512] (feat phase) — disjoint in time
//   [34934784) hbf       bf16[16384][512]
// ---------------------------------------------------------------------------
extern "C" void kernel_launch(void* const* d_in, const int* in_sizes, int n_in,
                              void* d_out, int out_size, void* d_ws, size_t ws_size,
                              hipStream_t stream){
  const float* x     = (const float*)d_in[0];
  const float* attn  = (const float*)d_in[1];
  const float* teach = (const float*)d_in[2];
  const float* Wemb  = (const float*)d_in[3];
  const float* bemb  = (const float*)d_in[4];
  const float* Wa1   = (const float*)d_in[5];
  const float* ba1   = (const float*)d_in[6];
  const float* Wa2   = (const float*)d_in[7];
  const float* ba2   = (const float*)d_in[8];
  const float* Wp    = (const float*)d_in[9];
  const float* bp    = (const float*)d_in[10];
  float* out = (float*)d_out;

  char* ws = (char*)d_ws;
  int*   keep = (int*)(ws + 0);
  float* s    = (float*)(ws + 65536);
  u16*   wet  = (u16*)(ws + 200704);
  u16*   wa1t = (u16*)(ws + 200704 + 1048576);
  char*  scr  = ws + 200704 + 1048576 + 131072;
  u16*   hbf  = (u16*)(ws + 200704 + 1048576 + 131072 + 33554432);

  int*   hist    = (int*)scr;
  int*   ctrl    = hist + 16384;
  float* partial = (float*)scr;   // reused after selection+gemm1

  k_prep<<<dim3(576), dim3(256), 0, stream>>>(Wemb, wet, Wa1, wa1t, hist);
  k_sel_hist<<<dim3(32), dim3(1024), 0, stream>>>(attn, hist);
  k_sel_scanrefine<<<dim3(1), dim3(1024), 0, stream>>>(attn, hist, ctrl);
  k_sel_cntwrite<<<dim3(32), dim3(1024), 0, stream>>>(attn, ctrl, keep);
  k_gemm1g<<<dim3(512), dim3(256), 0, stream>>>(x, keep, wet, bemb, hbf);
  k_gemm2<<<dim3(LKEEP / 64), dim3(256), 0, stream>>>(hbf, wa1t, ba1, Wa2, ba2, s);
  k_feat1<<<dim3(8, 64), dim3(256), 0, stream>>>(hbf, s, partial);
  k_final<<<dim3(1), dim3(512), 0, stream>>>(partial, teach, Wp, bp, out);
}

// Round 9
// 155.822 us; speedup vs baseline: 1.0649x; 1.0649x over previous
//
#include <hip/hip_runtime.h>
#include <hip/hip_cooperative_groups.h>
#include <hip/hip_bf16.h>
#include <math.h>

namespace cg = cooperative_groups;

// Problem constants
#define PS    32768
#define DIN   1024
#define DMID  512
#define DATT  128
#define KMASK 16384
#define LKEEP 16384

typedef unsigned short u16;
typedef __attribute__((ext_vector_type(8))) short short8;
typedef __attribute__((ext_vector_type(4))) float f32x4;

__device__ __forceinline__ u16 f2bf(float f){
  unsigned x = __float_as_uint(f);
  unsigned r = (x + 0x7fffu + ((x >> 16) & 1u)) >> 16;  // RNE
  return (u16)r;
}
__device__ __forceinline__ u16 f2bf_hw(float f){
  __hip_bfloat16 h = __float2bfloat16(f);
  return *reinterpret_cast<u16*>(&h);
}
__device__ __forceinline__ float bf2f(u16 u){
  return __uint_as_float(((unsigned)u) << 16);
}
__device__ __forceinline__ unsigned fkey(float f){
  unsigned b = __float_as_uint(f);
  return (b & 0x80000000u) ? ~b : (b | 0x80000000u);
}

#define GLDS16(g,l) __builtin_amdgcn_global_load_lds( \
    (const __attribute__((address_space(1))) void*)(g), \
    (__attribute__((address_space(3))) void*)(l), 16, 0, 0)

// ===========================================================================
// PART 1: cooperative mega-kernel (512 blocks x 256 thr, 2 blocks/CU forced)
// ===========================================================================
union SMem {
  struct { float tile[32][33]; } prep;
  struct { int suf[256]; unsigned ck[2048]; int ci[2048]; int misc[8]; } scan;
  struct { int ired[256]; } cw;
  struct { u16 As[128*32]; u16 Bs[128*32]; } g1;
  struct { u16 As[64*32];  u16 Bs[128*32]; } g2;
  struct { float r1[256]; float red[256*8]; } ft;
  struct { float red[256]; } fin;
};

#define TREE256_MAX(val, res) { sm.fin.red[t] = (val); __syncthreads(); \
  for (int st_ = 128; st_ >= 1; st_ >>= 1){ if (t < st_) sm.fin.red[t] = fmaxf(sm.fin.red[t], sm.fin.red[t+st_]); __syncthreads(); } \
  res = sm.fin.red[0]; __syncthreads(); }
#define TREE256_SUM(val, res) { sm.fin.red[t] = (val); __syncthreads(); \
  for (int st_ = 128; st_ >= 1; st_ >>= 1){ if (t < st_) sm.fin.red[t] += sm.fin.red[t+st_]; __syncthreads(); } \
  res = sm.fin.red[0]; __syncthreads(); }

__global__ __launch_bounds__(256, 2) void k_mega(
    const float* x, const float* attn, const float* teach,
    const float* Wemb, const float* bemb, const float* Wa1, const float* ba1,
    const float* Wa2, const float* ba2, const float* Wp, const float* bp,
    float* out, int* keep, float* s, u16* wet, u16* wa1t,
    int* hist, int* ctrl, float* partial, float* smax, float* ssum, u16* hbf)
{
  __shared__ SMem sm;
  cg::grid_group grid = cg::this_grid();
  const int b = blockIdx.x, t = threadIdx.x;
  const int wid = t >> 6, lane = t & 63;

  // ---- phase 0: weight transposes (f32->bf16) + zero hist/ctrl ------------
  {
    const int flat = b * 256 + t;
    if (flat < 16384 + 64) hist[flat] = 0;
    const int tx = t & 31, ty = t >> 5;
    for (int u = b; u < 576; u += 512){
      __syncthreads();
      if (u < 512){
        const int c0 = (u & 15) * 32, r0 = (u >> 4) * 32;   // Wemb [1024][512]
        for (int i2 = 0; i2 < 32; i2 += 8)
          sm.prep.tile[ty + i2][tx] = Wemb[(size_t)(r0 + ty + i2) * DMID + c0 + tx];
        __syncthreads();
        for (int i2 = 0; i2 < 32; i2 += 8)
          wet[(size_t)(c0 + ty + i2) * DIN + r0 + tx] = f2bf(sm.prep.tile[tx][ty + i2]);
      } else {
        const int b2 = u - 512;                              // Wa1 [512][128]
        const int c0 = (b2 & 3) * 32, r0 = (b2 >> 2) * 32;
        for (int i2 = 0; i2 < 32; i2 += 8)
          sm.prep.tile[ty + i2][tx] = Wa1[(size_t)(r0 + ty + i2) * DATT + c0 + tx];
        __syncthreads();
        for (int i2 = 0; i2 < 32; i2 += 8)
          wa1t[(size_t)(c0 + ty + i2) * DMID + r0 + tx] = f2bf(sm.prep.tile[tx][ty + i2]);
      }
    }
  }
  grid.sync();

  // ---- phase 1: 14-bit histogram ------------------------------------------
  {
    const int i = b * 256 + t;
    if (i < PS) atomicAdd(&hist[fkey(attn[i]) >> 18], 1);
  }
  grid.sync();

  // ---- phase 2: scan + refine (block 0) -----------------------------------
  if (b == 0){
    int psum = 0;
    const int base = t * 64;
    for (int j = 0; j < 64; j++) psum += hist[base + j];
    sm.scan.suf[t] = psum; __syncthreads();
    for (int off = 1; off < 256; off <<= 1){
      int v = (t + off < 256) ? sm.scan.suf[t + off] : 0;
      __syncthreads();
      sm.scan.suf[t] += v;
      __syncthreads();
    }
    const int above = (t < 255) ? sm.scan.suf[t + 1] : 0;
    if (above < KMASK && KMASK <= sm.scan.suf[t]){
      int cum = above;
      for (int bb = 63; bb >= 0; bb--){
        int c = hist[base + bb];
        if (cum + c >= KMASK){ sm.scan.misc[0] = base + bb; sm.scan.misc[1] = KMASK - cum; break; }
        cum += c;
      }
    }
    if (t == 0) sm.scan.misc[2] = 0;
    __syncthreads();
    const unsigned B = (unsigned)sm.scan.misc[0];
    const int kp = sm.scan.misc[1];
    for (int i = t; i < PS; i += 256){
      unsigned u = fkey(attn[i]);
      if ((u >> 18) == B){
        int p = atomicAdd(&sm.scan.misc[2], 1);
        if (p < 2048){ sm.scan.ck[p] = u; sm.scan.ci[p] = i; }
      }
    }
    __syncthreads();
    int n = sm.scan.misc[2]; if (n > 2048) n = 2048;
    for (int p = t; p < n; p += 256){
      const unsigned mk = sm.scan.ck[p]; const int mi = sm.scan.ci[p];
      int rank = 0;
      for (int j = 0; j < n; j++){
        const unsigned kj = sm.scan.ck[j];
        rank += (kj > mk) || (kj == mk && sm.scan.ci[j] < mi);
      }
      if (rank == kp - 1){ ctrl[2] = (int)mk; ctrl[3] = mi; }
    }
  }
  grid.sync();

  // ---- phase 3: stable compaction (512 x 64-elem chunks) ------------------
  {
    const unsigned C = (unsigned)ctrl[2];
    const int thr = ctrl[3];
    bool kept = false;
    const int i0 = b * 64 + t;
    if (t < 64){
      const unsigned u = fkey(attn[i0]);
      kept = (u < C) || (u == C && i0 > thr);
    }
    const unsigned long long bal = __ballot(kept);
    int cnt = 0;
    for (int i = t; i < b * 64; i += 256){
      const unsigned u2 = fkey(attn[i]);
      cnt += (u2 < C) || (u2 == C && i > thr);
    }
    sm.cw.ired[t] = cnt; __syncthreads();
    for (int st = 128; st >= 1; st >>= 1){ if (t < st) sm.cw.ired[t] += sm.cw.ired[t + st]; __syncthreads(); }
    const int base = sm.cw.ired[0];
    if (t < 64 && kept){
      const int lr = __popcll(bal & ((1ull << t) - 1ull));
      keep[base + lr] = i0;
    }
  }
  grid.sync();

  // ---- phase 4: GEMM1 fused gather ----------------------------------------
  {
    const int m_ = b;
    const int by = (m_ & 7) + 8 * (m_ >> 5);
    const int bx = (m_ >> 3) & 3;
    const int brow = by * 128, bcol = bx * 128;
    const int gq = lane >> 4, li = lane & 15;
    const int wrow0 = (wid >> 1) * 64, wcol0 = (wid & 1) * 64;

    f32x4 acc[4][4];
    for (int mm = 0; mm < 4; mm++)
      for (int nn = 0; nn < 4; nn++)
        acc[mm][nn] = (f32x4){0.f, 0.f, 0.f, 0.f};

    const int rsub = t >> 3, csub = t & 7;
    const float* gA[4];
#pragma unroll
    for (int q = 0; q < 4; q++){
      const int rid = keep[brow + q * 32 + rsub];
      gA[q] = x + (size_t)rid * DIN + csub * 4;
    }
    const int r4 = lane >> 2, cB = lane & 3;
    const u16* gB = wet + ((size_t)(bcol + wid * 32 + r4) * DIN + cB * 8);
    u16* lB = sm.g1.Bs + wid * 1024;

    for (int k0 = 0; k0 < DIN; k0 += 32){
      float4 av[4];
#pragma unroll
      for (int q = 0; q < 4; q++) av[q] = *(const float4*)(gA[q] + k0);
      GLDS16(gB + k0,            lB);
      GLDS16(gB + 16 * DIN + k0, lB + 512);
#pragma unroll
      for (int q = 0; q < 4; q++){
        ushort4 pk;
        pk.x = f2bf_hw(av[q].x); pk.y = f2bf_hw(av[q].y);
        pk.z = f2bf_hw(av[q].z); pk.w = f2bf_hw(av[q].w);
        *(ushort4*)&sm.g1.As[(q * 32 + rsub) * 32 + csub * 4] = pk;
      }
      __syncthreads();
      short8 a[4], bb[4];
#pragma unroll
      for (int mm = 0; mm < 4; mm++)
        a[mm] = *(const short8*)&sm.g1.As[(wrow0 + mm * 16 + li) * 32 + gq * 8];
#pragma unroll
      for (int nn = 0; nn < 4; nn++)
        bb[nn] = *(const short8*)&sm.g1.Bs[(wcol0 + nn * 16 + li) * 32 + gq * 8];
      for (int mm = 0; mm < 4; mm++)
        for (int nn = 0; nn < 4; nn++)
          acc[mm][nn] = __builtin_amdgcn_mfma_f32_16x16x32_bf16(a[mm], bb[nn], acc[mm][nn], 0, 0, 0);
      __syncthreads();
    }

    for (int nn = 0; nn < 4; nn++){
      const int col = bcol + wcol0 + nn * 16 + li;
      const float be = bemb[col];
      for (int mm = 0; mm < 4; mm++){
        const int row0 = brow + wrow0 + mm * 16 + gq * 4;
        f32x4 v = acc[mm][nn];
        for (int r = 0; r < 4; r++){
          float val = v[r] + be;
          if (val < 0.f) val = 0.f;
          hbf[(size_t)(row0 + r) * DMID + col] = f2bf(val);
        }
      }
    }
  }
  grid.sync();

  // ---- phase 5: GEMM2 + gelu + Wa2 dot -> s; per-64-row softmax stats -----
  if (b < 256){
    const int gq = lane >> 4, li = lane & 15;
    const int brow = b * 64;
    const int wrow0 = (wid >> 1) * 32, wcol0 = (wid & 1) * 64;

    f32x4 acc[2][4];
    for (int m = 0; m < 2; m++)
      for (int n = 0; n < 4; n++)
        acc[m][n] = (f32x4){0.f, 0.f, 0.f, 0.f};

    const int r4 = lane >> 2, c4 = lane & 3;
    const u16* gA = hbf  + ((size_t)(brow + wid * 16 + r4) * DMID + c4 * 8);
    const u16* gB = wa1t + ((size_t)(wid * 32 + r4) * DMID + c4 * 8);
    u16* lA = sm.g2.As + wid * 512;
    u16* lB = sm.g2.Bs + wid * 1024;

    for (int k0 = 0; k0 < DMID; k0 += 32){
      GLDS16(gA + k0,             lA);
      GLDS16(gB + k0,             lB);
      GLDS16(gB + 16 * DMID + k0, lB + 512);
      __syncthreads();
      short8 a[2], bb[4];
      for (int m = 0; m < 2; m++)
        a[m] = *(const short8*)&sm.g2.As[(wrow0 + m * 16 + li) * 32 + gq * 8];
      for (int n = 0; n < 4; n++)
        bb[n] = *(const short8*)&sm.g2.Bs[(wcol0 + n * 16 + li) * 32 + gq * 8];
      for (int m = 0; m < 2; m++)
        for (int n = 0; n < 4; n++)
          acc[m][n] = __builtin_amdgcn_mfma_f32_16x16x32_bf16(a[m], bb[n], acc[m][n], 0, 0, 0);
      __syncthreads();
    }

    float rsum[2][4] = {{0.f,0.f,0.f,0.f},{0.f,0.f,0.f,0.f}};
    for (int n = 0; n < 4; n++){
      const int col = wcol0 + n * 16 + li;
      const float b1 = ba1[col], w2 = Wa2[col];
      for (int m = 0; m < 2; m++){
        f32x4 v = acc[m][n];
        for (int r = 0; r < 4; r++){
          float xv = v[r] + b1;
          float ge = 0.5f * xv * (1.0f + erff(xv * 0.70710678118654752f));
          rsum[m][r] += ge * w2;
        }
      }
    }
    const float bb2 = ba2[0];
    for (int m = 0; m < 2; m++){
      for (int r = 0; r < 4; r++){
        float v = rsum[m][r];
        v += __shfl_xor(v, 1); v += __shfl_xor(v, 2);
        v += __shfl_xor(v, 4); v += __shfl_xor(v, 8);
        if (li == 0) s[brow + wrow0 + m * 16 + gq * 4 + r] = v + bb2;
      }
    }
    __syncthreads();
    if (t < 64){
      const float sv = s[brow + t];
      float mx = sv;
      for (int off = 1; off < 64; off <<= 1) mx = fmaxf(mx, __shfl_xor(mx, off));
      float ez = expf(sv - mx);
      for (int off = 1; off < 64; off <<= 1) ez += __shfl_xor(ez, off);
      if (t == 0){ smax[b] = mx; ssum[b] = ez; }
    }
  }
  grid.sync();

  // ---- phase 6: feat partials (redundant softmax-stat combine) ------------
  {
    float mb = smax[t];
    sm.ft.r1[t] = mb; __syncthreads();
    for (int st = 128; st >= 1; st >>= 1){ if (t < st) sm.ft.r1[t] = fmaxf(sm.ft.r1[t], sm.ft.r1[t + st]); __syncthreads(); }
    const float m = sm.ft.r1[0]; __syncthreads();
    float zb = ssum[t] * expf(smax[t] - m);
    sm.ft.r1[t] = zb; __syncthreads();
    for (int st = 128; st >= 1; st >>= 1){ if (t < st) sm.ft.r1[t] += sm.ft.r1[t + st]; __syncthreads(); }
    const float invZ = 1.0f / sm.ft.r1[0]; __syncthreads();

    const int colg = t & 7, rowpar = t >> 3;
    const int c0 = (b & 7) * 64;
    const int j0 = (b >> 3) * 256;
    float accf[8] = {0.f,0.f,0.f,0.f,0.f,0.f,0.f,0.f};
    for (int j = j0 + rowpar; j < j0 + 256; j += 32){
      const float wj = expf(s[j] - m) * invZ;
      short8 hv = *(const short8*)&hbf[(size_t)j * DMID + c0 + colg * 8];
      for (int c = 0; c < 8; c++) accf[c] += wj * bf2f((u16)hv[c]);
    }
    for (int c = 0; c < 8; c++) sm.ft.red[t * 8 + c] = accf[c];
    __syncthreads();
    for (int st = 128; st >= 8; st >>= 1){
      if (t < st){ for (int c = 0; c < 8; c++) sm.ft.red[t * 8 + c] += sm.ft.red[(t + st) * 8 + c]; }
      __syncthreads();
    }
    if (t < 8){
      for (int c = 0; c < 8; c++)
        partial[(size_t)(b >> 3) * DMID + c0 + t * 8 + c] = sm.ft.red[t * 8 + c];
    }
  }
  grid.sync();

  // ---- phase 7: final logits + soft-CE loss (block 0) ---------------------
  if (b == 0){
    float f0 = 0.f, f1 = 0.f;
    for (int rb = 0; rb < 64; rb++){
      f0 += partial[(size_t)rb * DMID + t];
      f1 += partial[(size_t)rb * DMID + t + 256];
    }
    const float td0 = teach[t], td1 = teach[t + 256];
    float mf, mt, Zf, Zt, S1, L0, L1;
    TREE256_MAX(fmaxf(f0, f1), mf);
    TREE256_MAX(fmaxf(td0, td1), mt);
    TREE256_SUM(expf(f0 - mf) + expf(f1 - mf), Zf);
    const float pt0 = expf(td0 - mt), pt1 = expf(td1 - mt);
    TREE256_SUM(pt0 + pt1, Zt);
    TREE256_SUM(pt0 * f0 + pt1 * f1, S1);
    TREE256_SUM(f0 * Wp[t * 2] + f1 * Wp[(t + 256) * 2], L0);
    TREE256_SUM(f0 * Wp[t * 2 + 1] + f1 * Wp[(t + 256) * 2 + 1], L1);
    if (t == 0){
      out[0] = L0 + bp[0];
      out[1] = L1 + bp[1];
      out[2] = (mf + logf(Zf)) - S1 / Zt;
    }
  }
}

// ===========================================================================
// PART 2: fallback — exact R6-proven 9-kernel pipeline (156.7 us)
// ===========================================================================
__global__ __launch_bounds__(256) void k_prep(const float* __restrict__ Wemb,
                                              u16* __restrict__ wet,
                                              const float* __restrict__ Wa1,
                                              u16* __restrict__ wa1t,
                                              int* __restrict__ zbuf){
  __shared__ float tile[32][33];
  const int b = blockIdx.x, t = threadIdx.x;
  const int flat = b * 256 + t;
  if (flat < 16384 + 64) zbuf[flat] = 0;
  const int tx = t & 31, ty = t >> 5;
  if (b < 512){
    const int c0 = (b & 15) * 32, r0 = (b >> 4) * 32;
    for (int i = 0; i < 32; i += 8)
      tile[ty + i][tx] = Wemb[(size_t)(r0 + ty + i) * DMID + c0 + tx];
    __syncthreads();
    for (int i = 0; i < 32; i += 8)
      wet[(size_t)(c0 + ty + i) * DIN + r0 + tx] = f2bf(tile[tx][ty + i]);
  } else {
    const int b2 = b - 512;
    const int c0 = (b2 & 3) * 32, r0 = (b2 >> 2) * 32;
    for (int i = 0; i < 32; i += 8)
      tile[ty + i][tx] = Wa1[(size_t)(r0 + ty + i) * DATT + c0 + tx];
    __syncthreads();
    for (int i = 0; i < 32; i += 8)
      wa1t[(size_t)(c0 + ty + i) * DMID + r0 + tx] = f2bf(tile[tx][ty + i]);
  }
}

__global__ __launch_bounds__(1024) void k_sel_hist(const float* __restrict__ attn,
                                                   int* __restrict__ hist){
  const int i = blockIdx.x * 1024 + threadIdx.x;
  const unsigned u = fkey(attn[i]);
  atomicAdd(&hist[u >> 18], 1);
}

__global__ __launch_bounds__(1024) void k_sel_scanrefine(const float* __restrict__ attn,
                                                         const int* __restrict__ hist,
                                                         int* __restrict__ ctrl){
  __shared__ int suf[1024];
  __shared__ unsigned ck[4096];
  __shared__ int ci[4096];
  __shared__ int sh_B, sh_kp, cnt;
  const int t = threadIdx.x;
  int local[16]; int s = 0;
  const int base = t * 16;
  for (int j = 0; j < 16; j++){ local[j] = hist[base + j]; s += local[j]; }
  suf[t] = s; __syncthreads();
  for (int off = 1; off < 1024; off <<= 1){
    int v = (t + off < 1024) ? suf[t + off] : 0;
    __syncthreads();
    suf[t] += v;
    __syncthreads();
  }
  const int above = (t < 1023) ? suf[t + 1] : 0;
  if (above < KMASK && KMASK <= suf[t]){
    int cum = above;
    for (int b = 15; b >= 0; b--){
      int c = local[b];
      if (cum + c >= KMASK){ sh_B = base + b; sh_kp = KMASK - cum; break; }
      cum += c;
    }
  }
  if (t == 0) cnt = 0;
  __syncthreads();
  const unsigned B = (unsigned)sh_B;
  const int kp = sh_kp;
  for (int i = t; i < PS; i += 1024){
    unsigned u = fkey(attn[i]);
    if ((u >> 18) == B){
      int p = atomicAdd(&cnt, 1);
      if (p < 4096){ ck[p] = u; ci[p] = i; }
    }
  }
  __syncthreads();
  int n = cnt; if (n > 4096) n = 4096;
  for (int p = t; p < n; p += 1024){
    const unsigned mk = ck[p]; const int mi = ci[p];
    int rank = 0;
    for (int j = 0; j < n; j++){
      const unsigned kj = ck[j];
      rank += (kj > mk) || (kj == mk && ci[j] < mi);
    }
    if (rank == kp - 1){ ctrl[2] = (int)mk; ctrl[3] = mi; }
  }
}

__global__ __launch_bounds__(1024) void k_sel_cntwrite(const float* __restrict__ attn,
                                                       const int* __restrict__ ctrl,
                                                       int* __restrict__ keep_ids){
  __shared__ int red[1024];
  __shared__ int wbase[16];
  __shared__ int sh_base;
  const int t = threadIdx.x, b = blockIdx.x;
  const unsigned C = (unsigned)ctrl[2];
  const int thr = ctrl[3];
  const int i = b * 1024 + t;
  const unsigned u = fkey(attn[i]);
  const bool kept = (u < C) || (u == C && i > thr);
  const unsigned long long bal = __ballot(kept);
  const int lane = t & 63, w = t >> 6;
  if (lane == 0) wbase[w] = __popcll(bal);
  int cnt = 0;
  for (int j = 0; j < b; j++){
    const int i2 = j * 1024 + t;
    const unsigned u2 = fkey(attn[i2]);
    cnt += (u2 < C) || (u2 == C && i2 > thr);
  }
  red[t] = cnt; __syncthreads();
  for (int st = 512; st > 0; st >>= 1){ if (t < st) red[t] += red[t + st]; __syncthreads(); }
  if (t == 0){
    sh_base = red[0];
    int run = 0;
    for (int j = 0; j < 16; j++){ int c = wbase[j]; wbase[j] = run; run += c; }
  }
  __syncthreads();
  if (kept){
    const int lr = __popcll(bal & ((1ull << lane) - 1ull));
    keep_ids[sh_base + wbase[w] + lr] = i;
  }
}

__global__ __launch_bounds__(256) void k_gemm1g(const float* __restrict__ xg,
                                                const int* __restrict__ keep,
                                                const u16* __restrict__ wet,
                                                const float* __restrict__ bemb,
                                                u16* __restrict__ hbf){
  __shared__ __align__(16) u16 As[128 * 32];
  __shared__ __align__(16) u16 Bs[128 * 32];
  const int t = threadIdx.x;
  const int wid = t >> 6, lane = t & 63;
  const int g = lane >> 4, li = lane & 15;
  const int m_ = blockIdx.x;
  const int by = (m_ & 7) + 8 * (m_ >> 5);
  const int bx = (m_ >> 3) & 3;
  const int brow = by * 128, bcol = bx * 128;
  const int wrow0 = (wid >> 1) * 64, wcol0 = (wid & 1) * 64;

  f32x4 acc[4][4];
  for (int mm = 0; mm < 4; mm++)
    for (int nn = 0; nn < 4; nn++)
      acc[mm][nn] = (f32x4){0.f, 0.f, 0.f, 0.f};

  const int rsub = t >> 3, csub = t & 7;
  const float* gA[4];
#pragma unroll
  for (int q = 0; q < 4; q++){
    const int rid = keep[brow + q * 32 + rsub];
    gA[q] = xg + (size_t)rid * DIN + csub * 4;
  }
  const int r4 = lane >> 2, cB = lane & 3;
  const u16* gB = wet + ((size_t)(bcol + wid * 32 + r4) * DIN + cB * 8);
  u16* lB = Bs + wid * 1024;

  for (int k0 = 0; k0 < DIN; k0 += 32){
    float4 av[4];
#pragma unroll
    for (int q = 0; q < 4; q++) av[q] = *(const float4*)(gA[q] + k0);
    GLDS16(gB + k0,            lB);
    GLDS16(gB + 16 * DIN + k0, lB + 512);
#pragma unroll
    for (int q = 0; q < 4; q++){
      ushort4 pk;
      pk.x = f2bf_hw(av[q].x); pk.y = f2bf_hw(av[q].y);
      pk.z = f2bf_hw(av[q].z); pk.w = f2bf_hw(av[q].w);
      *(ushort4*)&As[(q * 32 + rsub) * 32 + csub * 4] = pk;
    }
    __syncthreads();
    short8 a[4], b[4];
#pragma unroll
    for (int mm = 0; mm < 4; mm++)
      a[mm] = *(const short8*)&As[(wrow0 + mm * 16 + li) * 32 + g * 8];
#pragma unroll
    for (int nn = 0; nn < 4; nn++)
      b[nn] = *(const short8*)&Bs[(wcol0 + nn * 16 + li) * 32 + g * 8];
    for (int mm = 0; mm < 4; mm++)
      for (int nn = 0; nn < 4; nn++)
        acc[mm][nn] = __builtin_amdgcn_mfma_f32_16x16x32_bf16(a[mm], b[nn], acc[mm][nn], 0, 0, 0);
    __syncthreads();
  }

  for (int nn = 0; nn < 4; nn++){
    const int col = bcol + wcol0 + nn * 16 + li;
    const float be = bemb[col];
    for (int mm = 0; mm < 4; mm++){
      const int row0 = brow + wrow0 + mm * 16 + g * 4;
      f32x4 v = acc[mm][nn];
      for (int r = 0; r < 4; r++){
        float val = v[r] + be;
        if (val < 0.f) val = 0.f;
        hbf[(size_t)(row0 + r) * DMID + col] = f2bf(val);
      }
    }
  }
}

__global__ __launch_bounds__(256) void k_gemm2(const u16* __restrict__ hbf,
                                               const u16* __restrict__ wa1t,
                                               const float* __restrict__ ba1,
                                               const float* __restrict__ wa2,
                                               const float* __restrict__ ba2,
                                               float* __restrict__ s_out){
  __shared__ __align__(16) u16 As[64 * 32];
  __shared__ __align__(16) u16 Bs[128 * 32];
  const int t = threadIdx.x;
  const int wid = t >> 6, lane = t & 63;
  const int g = lane >> 4, li = lane & 15;
  const int brow = blockIdx.x * 64;
  const int wrow0 = (wid >> 1) * 32, wcol0 = (wid & 1) * 64;

  f32x4 acc[2][4];
  for (int m = 0; m < 2; m++)
    for (int n = 0; n < 4; n++)
      acc[m][n] = (f32x4){0.f, 0.f, 0.f, 0.f};

  const int r4 = lane >> 2, c4 = lane & 3;
  const u16* gA = hbf  + ((size_t)(brow + wid * 16 + r4) * DMID + c4 * 8);
  const u16* gB = wa1t + ((size_t)(wid * 32 + r4) * DMID + c4 * 8);
  u16* lA = As + wid * 512;
  u16* lB = Bs + wid * 1024;

  for (int k0 = 0; k0 < DMID; k0 += 32){
    GLDS16(gA + k0,             lA);
    GLDS16(gB + k0,             lB);
    GLDS16(gB + 16 * DMID + k0, lB + 512);
    __syncthreads();
    short8 a[2], b[4];
    for (int m = 0; m < 2; m++)
      a[m] = *(const short8*)&As[(wrow0 + m * 16 + li) * 32 + g * 8];
    for (int n = 0; n < 4; n++)
      b[n] = *(const short8*)&Bs[(wcol0 + n * 16 + li) * 32 + g * 8];
    for (int m = 0; m < 2; m++)
      for (int n = 0; n < 4; n++)
        acc[m][n] = __builtin_amdgcn_mfma_f32_16x16x32_bf16(a[m], b[n], acc[m][n], 0, 0, 0);
    __syncthreads();
  }

  float rsum[2][4] = {{0.f,0.f,0.f,0.f},{0.f,0.f,0.f,0.f}};
  for (int n = 0; n < 4; n++){
    const int col = wcol0 + n * 16 + li;
    const float b1 = ba1[col], w2 = wa2[col];
    for (int m = 0; m < 2; m++){
      f32x4 v = acc[m][n];
      for (int r = 0; r < 4; r++){
        float xv = v[r] + b1;
        float ge = 0.5f * xv * (1.0f + erff(xv * 0.70710678118654752f));
        rsum[m][r] += ge * w2;
      }
    }
  }
  const float bb = ba2[0];
  for (int m = 0; m < 2; m++){
    for (int r = 0; r < 4; r++){
      float v = rsum[m][r];
      v += __shfl_xor(v, 1); v += __shfl_xor(v, 2);
      v += __shfl_xor(v, 4); v += __shfl_xor(v, 8);
      if (li == 0) s_out[brow + wrow0 + m * 16 + g * 4 + r] = v + bb;
    }
  }
}

__global__ __launch_bounds__(1024) void k_softmax(const float* __restrict__ s,
                                                  float* __restrict__ w){
  __shared__ float red[1024];
  const int t = threadIdx.x;
  float m = -INFINITY;
  for (int i = t; i < LKEEP; i += 1024) m = fmaxf(m, s[i]);
  red[t] = m; __syncthreads();
  for (int st = 512; st > 0; st >>= 1){ if (t < st) red[t] = fmaxf(red[t], red[t + st]); __syncthreads(); }
  m = red[0]; __syncthreads();
  float z = 0.f;
  for (int i = t; i < LKEEP; i += 1024) z += expf(s[i] - m);
  red[t] = z; __syncthreads();
  for (int st = 512; st > 0; st >>= 1){ if (t < st) red[t] += red[t + st]; __syncthreads(); }
  const float invZ = 1.0f / red[0];
  for (int i = t; i < LKEEP; i += 1024) w[i] = expf(s[i] - m) * invZ;
}

__global__ __launch_bounds__(256) void k_feat1(const u16* __restrict__ hbf,
                                               const float* __restrict__ w,
                                               float* __restrict__ partial){
  const int t = threadIdx.x;
  const int colg = t & 7, rowpar = t >> 3;
  const int c0 = blockIdx.x * 64;
  const int j0 = blockIdx.y * 256;
  float acc[8] = {0.f};
  for (int j = j0 + rowpar; j < j0 + 256; j += 32){
    const float wj = w[j];
    short8 hv = *(const short8*)&hbf[(size_t)j * DMID + c0 + colg * 8];
    for (int c = 0; c < 8; c++) acc[c] += wj * bf2f((u16)hv[c]);
  }
  __shared__ float red[256 * 8];
  for (int c = 0; c < 8; c++) red[t * 8 + c] = acc[c];
  __syncthreads();
  for (int st = 128; st >= 8; st >>= 1){
    if (t < st){ for (int c = 0; c < 8; c++) red[t * 8 + c] += red[(t + st) * 8 + c]; }
    __syncthreads();
  }
  if (t < 8){
    for (int c = 0; c < 8; c++)
      partial[(size_t)blockIdx.y * DMID + c0 + t * 8 + c] = red[t * 8 + c];
  }
}

__global__ __launch_bounds__(512) void k_final(const float* __restrict__ partial,
                                               const float* __restrict__ teach,
                                               const float* __restrict__ Wp,
                                               const float* __restrict__ bp,
                                               float* __restrict__ out){
  __shared__ float red[512];
  const int t = threadIdx.x;
  float f = 0.f;
  for (int rb = 0; rb < 64; rb++) f += partial[(size_t)rb * DMID + t];
  const float td = teach[t];

  red[t] = f; __syncthreads();
  for (int st = 256; st > 0; st >>= 1){ if (t < st) red[t] = fmaxf(red[t], red[t + st]); __syncthreads(); }
  const float mf = red[0]; __syncthreads();

  red[t] = td; __syncthreads();
  for (int st = 256; st > 0; st >>= 1){ if (t < st) red[t] = fmaxf(red[t], red[t + st]); __syncthreads(); }
  const float mt = red[0]; __syncthreads();

  red[t] = expf(f - mf); __syncthreads();
  for (int st = 256; st > 0; st >>= 1){ if (t < st) red[t] += red[t + st]; __syncthreads(); }
  const float Zf = red[0]; __syncthreads();

  const float pt = expf(td - mt);
  red[t] = pt; __syncthreads();
  for (int st = 256; st > 0; st >>= 1){ if (t < st) red[t] += red[t + st]; __syncthreads(); }
  const float Zt = red[0]; __syncthreads();

  red[t] = pt * f; __syncthreads();
  for (int st = 256; st > 0; st >>= 1){ if (t < st) red[t] += red[t + st]; __syncthreads(); }
  const float S1 = red[0]; __syncthreads();

  red[t] = f * Wp[t * 2 + 0]; __syncthreads();
  for (int st = 256; st > 0; st >>= 1){ if (t < st) red[t] += red[t + st]; __syncthreads(); }
  const float L0 = red[0]; __syncthreads();

  red[t] = f * Wp[t * 2 + 1]; __syncthreads();
  for (int st = 256; st > 0; st >>= 1){ if (t < st) red[t] += red[t + st]; __syncthreads(); }
  const float L1 = red[0];

  if (t == 0){
    out[0] = L0 + bp[0];
    out[1] = L1 + bp[1];
    out[2] = (mf + logf(Zf)) - S1 / Zt;
  }
}

// ---------------------------------------------------------------------------
// ws layout (bytes):
//   [0)        keep_ids int[16384] | [65536) s f32[16384] | [131072) wgt f32[16384]
//   [200704)   wet bf16[512][1024] | [1249280) wa1t bf16[128][512]
//   [1380352)  scr: hist int[16384] + ctrl int[64] (selection);
//              partial f32[64][512] @+0 (feat); smax @+262144, ssum @+264192
//   [34934784) hbf bf16[16384][512]
// ---------------------------------------------------------------------------
extern "C" void kernel_launch(void* const* d_in, const int* in_sizes, int n_in,
                              void* d_out, int out_size, void* d_ws, size_t ws_size,
                              hipStream_t stream){
  const float* x     = (const float*)d_in[0];
  const float* attn  = (const float*)d_in[1];
  const float* teach = (const float*)d_in[2];
  const float* Wemb  = (const float*)d_in[3];
  const float* bemb  = (const float*)d_in[4];
  const float* Wa1   = (const float*)d_in[5];
  const float* ba1   = (const float*)d_in[6];
  const float* Wa2   = (const float*)d_in[7];
  const float* ba2   = (const float*)d_in[8];
  const float* Wp    = (const float*)d_in[9];
  const float* bp    = (const float*)d_in[10];
  float* out = (float*)d_out;

  char* ws = (char*)d_ws;
  int*   keep = (int*)(ws + 0);
  float* s    = (float*)(ws + 65536);
  float* wgt  = (float*)(ws + 131072);
  u16*   wet  = (u16*)(ws + 200704);
  u16*   wa1t = (u16*)(ws + 200704 + 1048576);
  char*  scr  = ws + 200704 + 1048576 + 131072;
  u16*   hbf  = (u16*)(ws + 200704 + 1048576 + 131072 + 33554432);

  int*   hist    = (int*)scr;
  int*   ctrl    = hist + 16384;
  float* partial = (float*)scr;
  float* smax    = (float*)(scr + 262144);
  float* ssum    = (float*)(scr + 264192);

  // --- capture-safe host-side prechecks for cooperative launch ---
  bool coop_ok = false;
  {
    int dev = 0;
    if (hipGetDevice(&dev) == hipSuccess){
      int attr = 0, ncu = 0, occ = 0;
      hipDeviceGetAttribute(&attr, hipDeviceAttributeCooperativeLaunch, dev);
      hipDeviceGetAttribute(&ncu, hipDeviceAttributeMultiprocessorCount, dev);
      if (attr &&
          hipOccupancyMaxActiveBlocksPerMultiprocessor(&occ, k_mega, 256, 0) == hipSuccess &&
          (long)occ * ncu >= 512){
        coop_ok = true;
      }
    }
  }

  bool launched = false;
  if (coop_ok){
    void* kargs[] = {
      (void*)&x, (void*)&attn, (void*)&teach, (void*)&Wemb, (void*)&bemb,
      (void*)&Wa1, (void*)&ba1, (void*)&Wa2, (void*)&ba2, (void*)&Wp, (void*)&bp,
      (void*)&out, (void*)&keep, (void*)&s, (void*)&wet, (void*)&wa1t,
      (void*)&hist, (void*)&ctrl, (void*)&partial, (void*)&smax, (void*)&ssum, (void*)&hbf
    };
    launched = (hipLaunchCooperativeKernel((const void*)k_mega, dim3(512), dim3(256),
                                           kargs, 0, stream) == hipSuccess);
  }

  if (!launched){
    // fallback: R6-proven 9-kernel pipeline
    k_prep<<<dim3(576), dim3(256), 0, stream>>>(Wemb, wet, Wa1, wa1t, hist);
    k_sel_hist<<<dim3(32), dim3(1024), 0, stream>>>(attn, hist);
    k_sel_scanrefine<<<dim3(1), dim3(1024), 0, stream>>>(attn, hist, ctrl);
    k_sel_cntwrite<<<dim3(32), dim3(1024), 0, stream>>>(attn, ctrl, keep);
    k_gemm1g<<<dim3(512), dim3(256), 0, stream>>>(x, keep, wet, bemb, hbf);
    k_gemm2<<<dim3(LKEEP / 64), dim3(256), 0, stream>>>(hbf, wa1t, ba1, Wa2, ba2, s);
    k_softmax<<<dim3(1), dim3(1024), 0, stream>>>(s, wgt);
    k_feat1<<<dim3(8, 64), dim3(256), 0, stream>>>(hbf, wgt, partial);
    k_final<<<dim3(1), dim3(512), 0, stream>>>(partial, teach, Wp, bp, out);
  }
}